// Round 1
// baseline (384.921 us; speedup 1.0000x reference)
//
#include <hip/hip_runtime.h>

#define NHEAD 12
#define DHEAD 64
#define SEQ 4096
#define BATCH 2
#define DMODEL 768
#define M_TOTAL (BATCH * SEQ)  // 8192

typedef __attribute__((ext_vector_type(8))) short bf16x8;
typedef __attribute__((ext_vector_type(4))) short s16x4;
typedef __attribute__((ext_vector_type(4))) float f32x4;
typedef unsigned short ushort_t;

__device__ __forceinline__ ushort_t f2bf(float f) {
  union { float f; unsigned u; } x; x.f = f;
  unsigned r = x.u + 0x7FFFu + ((x.u >> 16) & 1u);
  return (ushort_t)(r >> 16);
}

// ---------------- Kernel A: QKV projection GEMM ----------------
// C[n,o] = sum_d X[n,d] * W[o,d]   (y = x @ W^T), output bf16 [8192][768]
#define BM 128
#define BN 128
#define BK 32

__global__ __launch_bounds__(256) void qkv_gemm(
    const float* __restrict__ X, const float* __restrict__ Wq,
    const float* __restrict__ Wk, const float* __restrict__ Wv,
    ushort_t* __restrict__ qkv) {
  __shared__ __align__(16) ushort_t As[BM][BK];
  __shared__ __align__(16) ushort_t Bs[BN][BK];

  const float* W = (blockIdx.z == 0) ? Wq : ((blockIdx.z == 1) ? Wk : Wv);
  ushort_t* out = qkv + (size_t)blockIdx.z * (size_t)M_TOTAL * DMODEL;

  const int tid = threadIdx.x;
  const int lane = tid & 63, wave = tid >> 6;
  const int wr = wave >> 1, wc = wave & 1;   // 2x2 waves, 64x64 each
  const int m0 = blockIdx.x * BM, n0 = blockIdx.y * BN;
  const int l15 = lane & 15, l4 = lane >> 4;

  f32x4 acc[4][4] = {};

  for (int k0 = 0; k0 < DMODEL; k0 += BK) {
    // stage A,B tiles: 128x32 fp32 -> bf16. 1024 float4 chunks each.
#pragma unroll
    for (int i = 0; i < 4; ++i) {
      int c = tid + i * 256;
      int row = c >> 3, col4 = c & 7;
      float4 a = *reinterpret_cast<const float4*>(
          &X[(size_t)(m0 + row) * DMODEL + k0 + col4 * 4]);
      float4 b = *reinterpret_cast<const float4*>(
          &W[(size_t)(n0 + row) * DMODEL + k0 + col4 * 4]);
      s16x4 ap, bp;
      ap[0] = (short)f2bf(a.x); ap[1] = (short)f2bf(a.y);
      ap[2] = (short)f2bf(a.z); ap[3] = (short)f2bf(a.w);
      bp[0] = (short)f2bf(b.x); bp[1] = (short)f2bf(b.y);
      bp[2] = (short)f2bf(b.z); bp[3] = (short)f2bf(b.w);
      *reinterpret_cast<s16x4*>(&As[row][col4 * 4]) = ap;
      *reinterpret_cast<s16x4*>(&Bs[row][col4 * 4]) = bp;
    }
    __syncthreads();

    bf16x8 af[4], bf[4];
#pragma unroll
    for (int mi = 0; mi < 4; ++mi)
      af[mi] = *reinterpret_cast<const bf16x8*>(&As[wr * 64 + mi * 16 + l15][l4 * 8]);
#pragma unroll
    for (int ni = 0; ni < 4; ++ni)
      bf[ni] = *reinterpret_cast<const bf16x8*>(&Bs[wc * 64 + ni * 16 + l15][l4 * 8]);
#pragma unroll
    for (int mi = 0; mi < 4; ++mi)
#pragma unroll
      for (int ni = 0; ni < 4; ++ni)
        acc[mi][ni] = __builtin_amdgcn_mfma_f32_16x16x32_bf16(
            af[mi], bf[ni], acc[mi][ni], 0, 0, 0);
    __syncthreads();
  }

#pragma unroll
  for (int mi = 0; mi < 4; ++mi)
#pragma unroll
    for (int ni = 0; ni < 4; ++ni)
#pragma unroll
      for (int r = 0; r < 4; ++r) {
        int row = m0 + wr * 64 + mi * 16 + l4 * 4 + r;
        int col = n0 + wc * 64 + ni * 16 + l15;
        out[(size_t)row * DMODEL + col] = f2bf(acc[mi][ni][r]);
      }
}

// ---------------- Kernel B: sigmoid attention ----------------
// per (b,h): O[q,dh] = sum_k sigmoid(Q.K^T/8 - log(S)) * V[k,dh]
#define BQ 128
#define KB 64

__global__ __launch_bounds__(256) void sig_attn(
    const ushort_t* __restrict__ qkv, float* __restrict__ out) {
  __shared__ __align__(16) ushort_t Ks[KB * DHEAD];     // swizzled [k][dh]
  __shared__ __align__(16) ushort_t Vt[DHEAD * KB];     // swizzled [dh][k]
  __shared__ __align__(16) ushort_t Ps[4][32 * KB];     // per-wave P

  const int bh = blockIdx.y;
  const int b = bh / NHEAD, h = bh % NHEAD;
  const size_t SZ = (size_t)M_TOTAL * DMODEL;
  const ushort_t* Qg = qkv;
  const ushort_t* Kg = qkv + SZ;
  const ushort_t* Vg = qkv + 2 * SZ;

  const int tid = threadIdx.x, lane = tid & 63, wave = tid >> 6;
  const int l15 = lane & 15, l4 = lane >> 4;
  const int q0 = blockIdx.x * BQ + wave * 32;
  const size_t rowbase = (size_t)(b * SEQ) * DMODEL + h * DHEAD;

  // Q fragments in registers: [mi][ks], fragment-ready from global
  bf16x8 qf[2][2];
#pragma unroll
  for (int mi = 0; mi < 2; ++mi)
#pragma unroll
    for (int ks = 0; ks < 2; ++ks)
      qf[mi][ks] = *reinterpret_cast<const bf16x8*>(
          &Qg[rowbase + (size_t)(q0 + mi * 16 + l15) * DMODEL + ks * 32 + l4 * 8]);

  f32x4 oacc[2][4] = {};
  const float c1 = -0.18033688f;  // -(1/8)*log2(e)
  const float c0 = 12.0f;         // log2(4096) = -bias*log2(e)

  for (int kt = 0; kt < SEQ; kt += KB) {
    // ---- stage K (swizzled) and V (transposed + swizzled) ----
#pragma unroll
    for (int i = 0; i < 2; ++i) {
      int c = tid + i * 256;          // 16B chunk id; 512 chunks = 64x64 bf16
      int row = c >> 3, c8 = c & 7;
      bf16x8 kv = *reinterpret_cast<const bf16x8*>(
          &Kg[rowbase + (size_t)(kt + row) * DMODEL + c8 * 8]);
      int dst = row * 64 + ((c8 * 8) ^ ((row & 7) << 3));
      *reinterpret_cast<bf16x8*>(&Ks[dst]) = kv;
      bf16x8 vv = *reinterpret_cast<const bf16x8*>(
          &Vg[rowbase + (size_t)(kt + row) * DMODEL + c8 * 8]);
#pragma unroll
      for (int j = 0; j < 8; ++j) {
        int dh = c8 * 8 + j;
        Vt[dh * 64 + (row ^ ((dh & 7) << 3))] = (ushort_t)vv[j];
      }
    }
    __syncthreads();

    // ---- S = Q @ K^T ----
    f32x4 s_acc[2][4] = {};
#pragma unroll
    for (int ks = 0; ks < 2; ++ks) {
      bf16x8 kf[4];
#pragma unroll
      for (int nt = 0; nt < 4; ++nt) {
        int row = nt * 16 + l15;
        kf[nt] = *reinterpret_cast<const bf16x8*>(
            &Ks[row * 64 + ((ks * 32 + l4 * 8) ^ ((row & 7) << 3))]);
      }
#pragma unroll
      for (int mi = 0; mi < 2; ++mi)
#pragma unroll
        for (int nt = 0; nt < 4; ++nt)
          s_acc[mi][nt] = __builtin_amdgcn_mfma_f32_16x16x32_bf16(
              qf[mi][ks], kf[nt], s_acc[mi][nt], 0, 0, 0);
    }

    // ---- P = sigmoid(S/8 + bias), write to per-wave LDS as bf16 ----
#pragma unroll
    for (int mi = 0; mi < 2; ++mi)
#pragma unroll
      for (int nt = 0; nt < 4; ++nt)
#pragma unroll
        for (int r = 0; r < 4; ++r) {
          float t = __builtin_fmaf(s_acc[mi][nt][r], c1, c0);
          float p = __builtin_amdgcn_rcpf(1.0f + __builtin_amdgcn_exp2f(t));
          int qrow = mi * 16 + l4 * 4 + r;
          int kcol = nt * 16 + l15;
          Ps[wave][qrow * 64 + (kcol ^ ((qrow & 7) << 3))] = f2bf(p);
        }

    // ---- O += P @ V ----
#pragma unroll
    for (int ks = 0; ks < 2; ++ks) {
      bf16x8 pa[2];
#pragma unroll
      for (int mi = 0; mi < 2; ++mi) {
        int row = mi * 16 + l15;
        pa[mi] = *reinterpret_cast<const bf16x8*>(
            &Ps[wave][row * 64 + ((ks * 32 + l4 * 8) ^ ((row & 7) << 3))]);
      }
#pragma unroll
      for (int dt = 0; dt < 4; ++dt) {
        int row = dt * 16 + l15;
        bf16x8 vb = *reinterpret_cast<const bf16x8*>(
            &Vt[row * 64 + ((ks * 32 + l4 * 8) ^ ((row & 7) << 3))]);
#pragma unroll
        for (int mi = 0; mi < 2; ++mi)
          oacc[mi][dt] = __builtin_amdgcn_mfma_f32_16x16x32_bf16(
              pa[mi], vb, oacc[mi][dt], 0, 0, 0);
      }
    }
    __syncthreads();
  }

  // ---- epilogue: fp32 out[b, s, h*64 + dh] ----
#pragma unroll
  for (int mi = 0; mi < 2; ++mi)
#pragma unroll
    for (int dt = 0; dt < 4; ++dt)
#pragma unroll
      for (int r = 0; r < 4; ++r) {
        int s = q0 + mi * 16 + l4 * 4 + r;
        int dcol = dt * 16 + l15;
        out[(size_t)(b * SEQ + s) * DMODEL + h * DHEAD + dcol] = oacc[mi][dt][r];
      }
}

extern "C" void kernel_launch(void* const* d_in, const int* in_sizes, int n_in,
                              void* d_out, int out_size, void* d_ws, size_t ws_size,
                              hipStream_t stream) {
  const float* X  = (const float*)d_in[0];
  const float* Wq = (const float*)d_in[1];
  const float* Wk = (const float*)d_in[2];
  const float* Wv = (const float*)d_in[3];
  ushort_t* qkv = (ushort_t*)d_ws;  // 3 * 8192 * 768 bf16 = ~38 MB

  dim3 gA(M_TOTAL / BM, DMODEL / BN, 3);
  qkv_gemm<<<gA, 256, 0, stream>>>(X, Wq, Wk, Wv, qkv);

  dim3 gB(SEQ / BQ, BATCH * NHEAD);
  sig_attn<<<gB, 256, 0, stream>>>(qkv, (float*)d_out);
}

// Round 9
// 352.359 us; speedup vs baseline: 1.0924x; 1.0924x over previous
//
#include <hip/hip_runtime.h>

#define NHEAD 12
#define DHEAD 64
#define SEQ 4096
#define BATCH 2
#define DMODEL 768
#define M_TOTAL (BATCH * SEQ)  // 8192

typedef __attribute__((ext_vector_type(8))) short bf16x8;
typedef __attribute__((ext_vector_type(4))) short s16x4;
typedef __attribute__((ext_vector_type(4))) float f32x4;
typedef unsigned short ushort_t;

__device__ __forceinline__ ushort_t f2bf(float f) {
  union { float f; unsigned u; } x; x.f = f;
  unsigned r = x.u + 0x7FFFu + ((x.u >> 16) & 1u);
  return (ushort_t)(r >> 16);
}

// ---------------- Kernel A: QKV projection GEMM (round-1 verbatim, PASSED) --
#define BM 128
#define BN 128
#define BK 32

__global__ __launch_bounds__(256) void qkv_gemm(
    const float* __restrict__ X, const float* __restrict__ Wq,
    const float* __restrict__ Wk, const float* __restrict__ Wv,
    ushort_t* __restrict__ qkv) {
  __shared__ __align__(16) ushort_t As[BM][BK];
  __shared__ __align__(16) ushort_t Bs[BN][BK];

  const float* W = (blockIdx.z == 0) ? Wq : ((blockIdx.z == 1) ? Wk : Wv);
  ushort_t* out = qkv + (size_t)blockIdx.z * (size_t)M_TOTAL * DMODEL;

  const int tid = threadIdx.x;
  const int lane = tid & 63, wave = tid >> 6;
  const int wr = wave >> 1, wc = wave & 1;
  const int m0 = blockIdx.x * BM, n0 = blockIdx.y * BN;
  const int l15 = lane & 15, l4 = lane >> 4;

  f32x4 acc[4][4] = {};

  for (int k0 = 0; k0 < DMODEL; k0 += BK) {
#pragma unroll
    for (int i = 0; i < 4; ++i) {
      int c = tid + i * 256;
      int row = c >> 3, col4 = c & 7;
      float4 a = *reinterpret_cast<const float4*>(
          &X[(size_t)(m0 + row) * DMODEL + k0 + col4 * 4]);
      float4 b = *reinterpret_cast<const float4*>(
          &W[(size_t)(n0 + row) * DMODEL + k0 + col4 * 4]);
      s16x4 ap, bp;
      ap[0] = (short)f2bf(a.x); ap[1] = (short)f2bf(a.y);
      ap[2] = (short)f2bf(a.z); ap[3] = (short)f2bf(a.w);
      bp[0] = (short)f2bf(b.x); bp[1] = (short)f2bf(b.y);
      bp[2] = (short)f2bf(b.z); bp[3] = (short)f2bf(b.w);
      *reinterpret_cast<s16x4*>(&As[row][col4 * 4]) = ap;
      *reinterpret_cast<s16x4*>(&Bs[row][col4 * 4]) = bp;
    }
    __syncthreads();

    bf16x8 af[4], bfr[4];
#pragma unroll
    for (int mi = 0; mi < 4; ++mi)
      af[mi] = *reinterpret_cast<const bf16x8*>(&As[wr * 64 + mi * 16 + l15][l4 * 8]);
#pragma unroll
    for (int ni = 0; ni < 4; ++ni)
      bfr[ni] = *reinterpret_cast<const bf16x8*>(&Bs[wc * 64 + ni * 16 + l15][l4 * 8]);
#pragma unroll
    for (int mi = 0; mi < 4; ++mi)
#pragma unroll
      for (int ni = 0; ni < 4; ++ni)
        acc[mi][ni] = __builtin_amdgcn_mfma_f32_16x16x32_bf16(
            af[mi], bfr[ni], acc[mi][ni], 0, 0, 0);
    __syncthreads();
  }

#pragma unroll
  for (int mi = 0; mi < 4; ++mi)
#pragma unroll
    for (int ni = 0; ni < 4; ++ni)
#pragma unroll
      for (int r = 0; r < 4; ++r) {
        int row = m0 + wr * 64 + mi * 16 + l4 * 4 + r;
        int col = n0 + wc * 64 + ni * 16 + l15;
        out[(size_t)row * DMODEL + col] = f2bf(acc[mi][ni][r]);
      }
}

// ---------------- Kernel B: sigmoid attention ----------------
// ROUND-1 VERBATIM (passed, 274us) except EXACTLY TWO swizzle-mask changes:
//   V: (dh&7)<<3 -> ((dh&7)^(dh>>3))<<3  [write 16-way -> 2-way bank conflict]
//   P: (qrow&7)<<3 -> ((qrow&7)^(qrow>>3))<<3
// Both are write/read-consistent bijections within a row. No prefetch
// restructure, no cvt_pk asm, no setprio (bisecting the r3/r4/r7 failure).
#define BQ 128
#define KB 64

__global__ __launch_bounds__(256) void sig_attn(
    const ushort_t* __restrict__ qkv, float* __restrict__ out) {
  __shared__ __align__(16) ushort_t Ks[KB * DHEAD];     // swizzled [k][dh]
  __shared__ __align__(16) ushort_t Vt[DHEAD * KB];     // swizzled [dh][k]
  __shared__ __align__(16) ushort_t Ps[4][32 * KB];     // per-wave P

  const int bh = blockIdx.y;
  const int b = bh / NHEAD, h = bh % NHEAD;
  const size_t SZ = (size_t)M_TOTAL * DMODEL;
  const ushort_t* Qg = qkv;
  const ushort_t* Kg = qkv + SZ;
  const ushort_t* Vg = qkv + 2 * SZ;

  const int tid = threadIdx.x, lane = tid & 63, wave = tid >> 6;
  const int l15 = lane & 15, l4 = lane >> 4;
  const int q0 = blockIdx.x * BQ + wave * 32;
  const size_t rowbase = (size_t)(b * SEQ) * DMODEL + h * DHEAD;

  // Q fragments in registers: [mi][ks], fragment-ready from global
  bf16x8 qf[2][2];
#pragma unroll
  for (int mi = 0; mi < 2; ++mi)
#pragma unroll
    for (int ks = 0; ks < 2; ++ks)
      qf[mi][ks] = *reinterpret_cast<const bf16x8*>(
          &Qg[rowbase + (size_t)(q0 + mi * 16 + l15) * DMODEL + ks * 32 + l4 * 8]);

  f32x4 oacc[2][4] = {};
  const float c1 = -0.18033688f;  // -(1/8)*log2(e)
  const float c0 = 12.0f;         // log2(4096) = -bias*log2(e)

  for (int kt = 0; kt < SEQ; kt += KB) {
    // ---- stage K (swizzled) and V (transposed + swizzled) ----
#pragma unroll
    for (int i = 0; i < 2; ++i) {
      int c = tid + i * 256;          // 16B chunk id; 512 chunks = 64x64 bf16
      int row = c >> 3, c8 = c & 7;
      bf16x8 kv = *reinterpret_cast<const bf16x8*>(
          &Kg[rowbase + (size_t)(kt + row) * DMODEL + c8 * 8]);
      int dst = row * 64 + ((c8 * 8) ^ ((row & 7) << 3));
      *reinterpret_cast<bf16x8*>(&Ks[dst]) = kv;
      bf16x8 vv = *reinterpret_cast<const bf16x8*>(
          &Vg[rowbase + (size_t)(kt + row) * DMODEL + c8 * 8]);
#pragma unroll
      for (int j = 0; j < 8; ++j) {
        int dh = c8 * 8 + j;
        Vt[dh * 64 + (row ^ ((j ^ c8) << 3))] = (ushort_t)vv[j];
      }
    }
    __syncthreads();

    // ---- S = Q @ K^T ----
    f32x4 s_acc[2][4] = {};
#pragma unroll
    for (int ks = 0; ks < 2; ++ks) {
      bf16x8 kf[4];
#pragma unroll
      for (int nt = 0; nt < 4; ++nt) {
        int row = nt * 16 + l15;
        kf[nt] = *reinterpret_cast<const bf16x8*>(
            &Ks[row * 64 + ((ks * 32 + l4 * 8) ^ ((row & 7) << 3))]);
      }
#pragma unroll
      for (int mi = 0; mi < 2; ++mi)
#pragma unroll
        for (int nt = 0; nt < 4; ++nt)
          s_acc[mi][nt] = __builtin_amdgcn_mfma_f32_16x16x32_bf16(
              qf[mi][ks], kf[nt], s_acc[mi][nt], 0, 0, 0);
    }

    // ---- P = sigmoid(S/8 + bias), write to per-wave LDS as bf16 ----
#pragma unroll
    for (int mi = 0; mi < 2; ++mi)
#pragma unroll
      for (int nt = 0; nt < 4; ++nt)
#pragma unroll
        for (int r = 0; r < 4; ++r) {
          float t = __builtin_fmaf(s_acc[mi][nt][r], c1, c0);
          float p = __builtin_amdgcn_rcpf(1.0f + __builtin_amdgcn_exp2f(t));
          int qrow = mi * 16 + l4 * 4 + r;
          int kcol = nt * 16 + l15;
          Ps[wave][qrow * 64 + (kcol ^ (((qrow & 7) ^ (qrow >> 3)) << 3))] = f2bf(p);
        }

    // ---- O += P @ V ----
#pragma unroll
    for (int ks = 0; ks < 2; ++ks) {
      bf16x8 pa[2];
#pragma unroll
      for (int mi = 0; mi < 2; ++mi) {
        int row = mi * 16 + l15;
        pa[mi] = *reinterpret_cast<const bf16x8*>(
            &Ps[wave][row * 64 +
                      ((ks * 32 + l4 * 8) ^ (((row & 7) ^ (row >> 3)) << 3))]);
      }
#pragma unroll
      for (int dt = 0; dt < 4; ++dt) {
        int row = dt * 16 + l15;
        bf16x8 vb = *reinterpret_cast<const bf16x8*>(
            &Vt[row * 64 +
                ((ks * 32 + l4 * 8) ^ (((row & 7) ^ (row >> 3)) << 3))]);
#pragma unroll
        for (int mi = 0; mi < 2; ++mi)
          oacc[mi][dt] = __builtin_amdgcn_mfma_f32_16x16x32_bf16(
              pa[mi], vb, oacc[mi][dt], 0, 0, 0);
      }
    }
    __syncthreads();
  }

  // ---- epilogue: fp32 out[b, s, h*64 + dh] ----
#pragma unroll
  for (int mi = 0; mi < 2; ++mi)
#pragma unroll
    for (int dt = 0; dt < 4; ++dt)
#pragma unroll
      for (int r = 0; r < 4; ++r) {
        int s = q0 + mi * 16 + l4 * 4 + r;
        int dcol = dt * 16 + l15;
        out[(size_t)(b * SEQ + s) * DMODEL + h * DHEAD + dcol] = oacc[mi][dt][r];
      }
}

extern "C" void kernel_launch(void* const* d_in, const int* in_sizes, int n_in,
                              void* d_out, int out_size, void* d_ws, size_t ws_size,
                              hipStream_t stream) {
  const float* X  = (const float*)d_in[0];
  const float* Wq = (const float*)d_in[1];
  const float* Wk = (const float*)d_in[2];
  const float* Wv = (const float*)d_in[3];
  ushort_t* qkv = (ushort_t*)d_ws;  // 3 * 8192 * 768 bf16 = ~38 MB

  dim3 gA(M_TOTAL / BM, DMODEL / BN, 3);
  qkv_gemm<<<gA, 256, 0, stream>>>(X, Wq, Wk, Wv, qkv);

  dim3 gB(SEQ / BQ, BATCH * NHEAD);
  sig_attn<<<gB, 256, 0, stream>>>(qkv, (float*)d_out);
}

// Round 10
// 331.724 us; speedup vs baseline: 1.1604x; 1.0622x over previous
//
#include <hip/hip_runtime.h>

#define NHEAD 12
#define DHEAD 64
#define SEQ 4096
#define BATCH 2
#define DMODEL 768
#define M_TOTAL (BATCH * SEQ)  // 8192

typedef __attribute__((ext_vector_type(8))) short bf16x8;
typedef __attribute__((ext_vector_type(4))) short s16x4;
typedef __attribute__((ext_vector_type(4))) float f32x4;
typedef __attribute__((ext_vector_type(2))) unsigned u32x2;
typedef unsigned short ushort_t;

__device__ __forceinline__ ushort_t f2bf(float f) {
  union { float f; unsigned u; } x; x.f = f;
  unsigned r = x.u + 0x7FFFu + ((x.u >> 16) & 1u);
  return (ushort_t)(r >> 16);
}

__device__ __forceinline__ unsigned cvt_pk_bf16(float lo, float hi) {
  unsigned r;
  asm("v_cvt_pk_bf16_f32 %0, %1, %2" : "=v"(r) : "v"(lo), "v"(hi));
  return r;
}

// ---------------- Kernel A: QKV projection GEMM ----------------
// Reworked this round (attn frozen at round-9-PASSED state):
//   * As/Bs leading dim padded 32 -> 40 elems (80B rows): fragment b128 reads
//     were ~16-way bank-conflicted (64B rows -> bank independent of row)
//   * staging + epilogue conversion via v_cvt_pk_bf16_f32 (1 op / 2 vals,
//     RNE like f2bf) instead of 4-op f2bf per value
//   * T14 register prefetch: next K-tile's global loads issued after the
//     post-write barrier, consumed next iteration
#define BM 128
#define BN 128
#define BK 32
#define BKP 40   // padded leading dim (elements)

__global__ __launch_bounds__(256) void qkv_gemm(
    const float* __restrict__ X, const float* __restrict__ Wq,
    const float* __restrict__ Wk, const float* __restrict__ Wv,
    ushort_t* __restrict__ qkv) {
  __shared__ __align__(16) ushort_t As[BM][BKP];
  __shared__ __align__(16) ushort_t Bs[BN][BKP];

  const float* W = (blockIdx.z == 0) ? Wq : ((blockIdx.z == 1) ? Wk : Wv);
  ushort_t* out = qkv + (size_t)blockIdx.z * (size_t)M_TOTAL * DMODEL;

  const int tid = threadIdx.x;
  const int lane = tid & 63, wave = tid >> 6;
  const int wr = wave >> 1, wc = wave & 1;
  const int m0 = blockIdx.x * BM, n0 = blockIdx.y * BN;
  const int l15 = lane & 15, l4 = lane >> 4;

  f32x4 acc[4][4] = {};

  // prologue: K-tile 0 -> registers
  float4 ar[4], br[4];
#pragma unroll
  for (int i = 0; i < 4; ++i) {
    int c = tid + i * 256;
    int row = c >> 3, col4 = c & 7;
    ar[i] = *reinterpret_cast<const float4*>(
        &X[(size_t)(m0 + row) * DMODEL + col4 * 4]);
    br[i] = *reinterpret_cast<const float4*>(
        &W[(size_t)(n0 + row) * DMODEL + col4 * 4]);
  }

  for (int k0 = 0; k0 < DMODEL; k0 += BK) {
    __syncthreads();   // previous iteration's fragment reads complete
#pragma unroll
    for (int i = 0; i < 4; ++i) {
      int c = tid + i * 256;
      int row = c >> 3, col4 = c & 7;
      u32x2 ap, bp;
      ap[0] = cvt_pk_bf16(ar[i].x, ar[i].y);
      ap[1] = cvt_pk_bf16(ar[i].z, ar[i].w);
      bp[0] = cvt_pk_bf16(br[i].x, br[i].y);
      bp[1] = cvt_pk_bf16(br[i].z, br[i].w);
      *reinterpret_cast<u32x2*>(&As[row][col4 * 4]) = ap;
      *reinterpret_cast<u32x2*>(&Bs[row][col4 * 4]) = bp;
    }
    __syncthreads();

    if (k0 + BK < DMODEL) {  // T14: prefetch next K-tile
#pragma unroll
      for (int i = 0; i < 4; ++i) {
        int c = tid + i * 256;
        int row = c >> 3, col4 = c & 7;
        ar[i] = *reinterpret_cast<const float4*>(
            &X[(size_t)(m0 + row) * DMODEL + k0 + BK + col4 * 4]);
        br[i] = *reinterpret_cast<const float4*>(
            &W[(size_t)(n0 + row) * DMODEL + k0 + BK + col4 * 4]);
      }
    }

    bf16x8 af[4], bfr[4];
#pragma unroll
    for (int mi = 0; mi < 4; ++mi)
      af[mi] = *reinterpret_cast<const bf16x8*>(&As[wr * 64 + mi * 16 + l15][l4 * 8]);
#pragma unroll
    for (int ni = 0; ni < 4; ++ni)
      bfr[ni] = *reinterpret_cast<const bf16x8*>(&Bs[wc * 64 + ni * 16 + l15][l4 * 8]);
#pragma unroll
    for (int mi = 0; mi < 4; ++mi)
#pragma unroll
      for (int ni = 0; ni < 4; ++ni)
        acc[mi][ni] = __builtin_amdgcn_mfma_f32_16x16x32_bf16(
            af[mi], bfr[ni], acc[mi][ni], 0, 0, 0);
  }

#pragma unroll
  for (int mi = 0; mi < 4; ++mi)
#pragma unroll
    for (int ni = 0; ni < 4; ++ni)
#pragma unroll
      for (int r = 0; r < 4; r += 2) {
        unsigned u = cvt_pk_bf16(acc[mi][ni][r], acc[mi][ni][r + 1]);
        int row = m0 + wr * 64 + mi * 16 + l4 * 4 + r;
        int col = n0 + wc * 64 + ni * 16 + l15;
        out[(size_t)row * DMODEL + col] = (ushort_t)(u & 0xffffu);
        out[(size_t)(row + 1) * DMODEL + col] = (ushort_t)(u >> 16);
      }
}

// ---------------- Kernel B: sigmoid attention (ROUND-9 VERBATIM, PASSED) ---
// 234.8us, bank conflicts 9.4e6, MfmaUtil 18.7. DO NOT TOUCH this round —
// attribution domain for any failure is qkv_gemm only.
#define BQ 128
#define KB 64

__global__ __launch_bounds__(256) void sig_attn(
    const ushort_t* __restrict__ qkv, float* __restrict__ out) {
  __shared__ __align__(16) ushort_t Ks[KB * DHEAD];     // swizzled [k][dh]
  __shared__ __align__(16) ushort_t Vt[DHEAD * KB];     // swizzled [dh][k]
  __shared__ __align__(16) ushort_t Ps[4][32 * KB];     // per-wave P

  const int bh = blockIdx.y;
  const int b = bh / NHEAD, h = bh % NHEAD;
  const size_t SZ = (size_t)M_TOTAL * DMODEL;
  const ushort_t* Qg = qkv;
  const ushort_t* Kg = qkv + SZ;
  const ushort_t* Vg = qkv + 2 * SZ;

  const int tid = threadIdx.x, lane = tid & 63, wave = tid >> 6;
  const int l15 = lane & 15, l4 = lane >> 4;
  const int q0 = blockIdx.x * BQ + wave * 32;
  const size_t rowbase = (size_t)(b * SEQ) * DMODEL + h * DHEAD;

  // Q fragments in registers: [mi][ks], fragment-ready from global
  bf16x8 qf[2][2];
#pragma unroll
  for (int mi = 0; mi < 2; ++mi)
#pragma unroll
    for (int ks = 0; ks < 2; ++ks)
      qf[mi][ks] = *reinterpret_cast<const bf16x8*>(
          &Qg[rowbase + (size_t)(q0 + mi * 16 + l15) * DMODEL + ks * 32 + l4 * 8]);

  f32x4 oacc[2][4] = {};
  const float c1 = -0.18033688f;  // -(1/8)*log2(e)
  const float c0 = 12.0f;         // log2(4096) = -bias*log2(e)

  for (int kt = 0; kt < SEQ; kt += KB) {
    // ---- stage K (swizzled) and V (transposed + swizzled) ----
#pragma unroll
    for (int i = 0; i < 2; ++i) {
      int c = tid + i * 256;          // 16B chunk id; 512 chunks = 64x64 bf16
      int row = c >> 3, c8 = c & 7;
      bf16x8 kv = *reinterpret_cast<const bf16x8*>(
          &Kg[rowbase + (size_t)(kt + row) * DMODEL + c8 * 8]);
      int dst = row * 64 + ((c8 * 8) ^ ((row & 7) << 3));
      *reinterpret_cast<bf16x8*>(&Ks[dst]) = kv;
      bf16x8 vv = *reinterpret_cast<const bf16x8*>(
          &Vg[rowbase + (size_t)(kt + row) * DMODEL + c8 * 8]);
#pragma unroll
      for (int j = 0; j < 8; ++j) {
        int dh = c8 * 8 + j;
        Vt[dh * 64 + (row ^ ((j ^ c8) << 3))] = (ushort_t)vv[j];
      }
    }
    __syncthreads();

    // ---- S = Q @ K^T ----
    f32x4 s_acc[2][4] = {};
#pragma unroll
    for (int ks = 0; ks < 2; ++ks) {
      bf16x8 kf[4];
#pragma unroll
      for (int nt = 0; nt < 4; ++nt) {
        int row = nt * 16 + l15;
        kf[nt] = *reinterpret_cast<const bf16x8*>(
            &Ks[row * 64 + ((ks * 32 + l4 * 8) ^ ((row & 7) << 3))]);
      }
#pragma unroll
      for (int mi = 0; mi < 2; ++mi)
#pragma unroll
        for (int nt = 0; nt < 4; ++nt)
          s_acc[mi][nt] = __builtin_amdgcn_mfma_f32_16x16x32_bf16(
              qf[mi][ks], kf[nt], s_acc[mi][nt], 0, 0, 0);
    }

    // ---- P = sigmoid(S/8 + bias), write to per-wave LDS as bf16 ----
#pragma unroll
    for (int mi = 0; mi < 2; ++mi)
#pragma unroll
      for (int nt = 0; nt < 4; ++nt)
#pragma unroll
        for (int r = 0; r < 4; ++r) {
          float t = __builtin_fmaf(s_acc[mi][nt][r], c1, c0);
          float p = __builtin_amdgcn_rcpf(1.0f + __builtin_amdgcn_exp2f(t));
          int qrow = mi * 16 + l4 * 4 + r;
          int kcol = nt * 16 + l15;
          Ps[wave][qrow * 64 + (kcol ^ (((qrow & 7) ^ (qrow >> 3)) << 3))] = f2bf(p);
        }

    // ---- O += P @ V ----
#pragma unroll
    for (int ks = 0; ks < 2; ++ks) {
      bf16x8 pa[2];
#pragma unroll
      for (int mi = 0; mi < 2; ++mi) {
        int row = mi * 16 + l15;
        pa[mi] = *reinterpret_cast<const bf16x8*>(
            &Ps[wave][row * 64 +
                      ((ks * 32 + l4 * 8) ^ (((row & 7) ^ (row >> 3)) << 3))]);
      }
#pragma unroll
      for (int dt = 0; dt < 4; ++dt) {
        int row = dt * 16 + l15;
        bf16x8 vb = *reinterpret_cast<const bf16x8*>(
            &Vt[row * 64 +
                ((ks * 32 + l4 * 8) ^ (((row & 7) ^ (row >> 3)) << 3))]);
#pragma unroll
        for (int mi = 0; mi < 2; ++mi)
          oacc[mi][dt] = __builtin_amdgcn_mfma_f32_16x16x32_bf16(
              pa[mi], vb, oacc[mi][dt], 0, 0, 0);
      }
    }
    __syncthreads();
  }

  // ---- epilogue: fp32 out[b, s, h*64 + dh] ----
#pragma unroll
  for (int mi = 0; mi < 2; ++mi)
#pragma unroll
    for (int dt = 0; dt < 4; ++dt)
#pragma unroll
      for (int r = 0; r < 4; ++r) {
        int s = q0 + mi * 16 + l4 * 4 + r;
        int dcol = dt * 16 + l15;
        out[(size_t)(b * SEQ + s) * DMODEL + h * DHEAD + dcol] = oacc[mi][dt][r];
      }
}

extern "C" void kernel_launch(void* const* d_in, const int* in_sizes, int n_in,
                              void* d_out, int out_size, void* d_ws, size_t ws_size,
                              hipStream_t stream) {
  const float* X  = (const float*)d_in[0];
  const float* Wq = (const float*)d_in[1];
  const float* Wk = (const float*)d_in[2];
  const float* Wv = (const float*)d_in[3];
  ushort_t* qkv = (ushort_t*)d_ws;  // 3 * 8192 * 768 bf16 = ~38 MB

  dim3 gA(M_TOTAL / BM, DMODEL / BN, 3);
  qkv_gemm<<<gA, 256, 0, stream>>>(X, Wq, Wk, Wv, qkv);

  dim3 gB(SEQ / BQ, BATCH * NHEAD);
  sig_attn<<<gB, 256, 0, stream>>>(qkv, (float*)d_out);
}